// Round 12
// baseline (58.239 us; speedup 1.0000x reference)
//
#include <hip/hip_runtime.h>
#include <stdint.h>

#define BB 8
#define NN 2048
#define CC 128
#define OO 128

typedef __attribute__((ext_vector_type(8))) short bf16x8;
typedef __attribute__((ext_vector_type(4))) float f32x4;
typedef __attribute__((ext_vector_type(4))) int i32x4;
typedef __attribute__((ext_vector_type(4))) unsigned short u16x4;
typedef unsigned int u32;
typedef unsigned short u16;

__device__ __forceinline__ u16 f2bf(float f) {
    union { float f; u32 u; } v; v.f = f;
    u32 r = v.u + 0x7FFFu + ((v.u >> 16) & 1u);
    return (u16)(r >> 16);
}

// ---------------------------------------------------------------------------
// Kernel 0: Wt[o][c] = bf16(W_lin[c][o]).  (proven R3-R11, verbatim)
// ---------------------------------------------------------------------------
__global__ __launch_bounds__(256) void wt_kernel(
    const float* __restrict__ W_lin, u16* __restrict__ Wt)
{
    __shared__ float ws2[8][132];
    const int t = threadIdx.x, o0 = blockIdx.x * 8;
    f32x4 v = *(const f32x4*)(W_lin + (t >> 1) * OO + o0 + (t & 1) * 4);
    #pragma unroll
    for (int e = 0; e < 4; ++e) ws2[(t & 1) * 4 + e][t >> 1] = v[e];
    __syncthreads();
    const int oo = t >> 5, c0 = (t & 31) * 4;
    f32x4 u = *(const f32x4*)&ws2[oo][c0];
    u16x4 h;
    #pragma unroll
    for (int e = 0; e < 4; ++e) h[e] = f2bf(u[e]);
    *(u16x4*)(Wt + (size_t)(o0 + oo) * CC + c0) = h;
}

// ---------------------------------------------------------------------------
// Kernel 1: precompute via MFMA, no LDS.  (proven R3-R11, verbatim)
// ---------------------------------------------------------------------------
__global__ __launch_bounds__(256) void precompute_kernel(
    const float* __restrict__ x, const float* __restrict__ W_fc,
    const float* __restrict__ b_fc, const u16* __restrict__ Wt,
    float* __restrict__ sj, float* __restrict__ sk, u16* __restrict__ Yt)
{
    const int t = threadIdx.x, l = t & 63, w = t >> 6;
    const int sl = l & 15, g = l >> 4;
    const int b  = blockIdx.x >> 6;
    const int k0 = (blockIdx.x & 63) << 5;
    const int mt = w & 1, nb = (w >> 1) << 2;
    const int row = k0 + mt * 16 + sl;
    const float* xr = x + ((size_t)(b * NN + row) << 7);

    bf16x8 a[4];
    float p1 = 0.f, p2 = 0.f;
    #pragma unroll
    for (int ks = 0; ks < 4; ++ks) {
        f32x4 lo4 = *(const f32x4*)(xr + ks * 32 + g * 8);
        f32x4 hi4 = *(const f32x4*)(xr + ks * 32 + g * 8 + 4);
        f32x4 w1l = *(const f32x4*)(W_fc + ks * 32 + g * 8);
        f32x4 w1h = *(const f32x4*)(W_fc + ks * 32 + g * 8 + 4);
        f32x4 w2l = *(const f32x4*)(W_fc + CC + ks * 32 + g * 8);
        f32x4 w2h = *(const f32x4*)(W_fc + CC + ks * 32 + g * 8 + 4);
        bf16x8 av;
        #pragma unroll
        for (int e = 0; e < 4; ++e) {
            p1 += lo4[e] * w1l[e] + hi4[e] * w1h[e];
            p2 += lo4[e] * w2l[e] + hi4[e] * w2h[e];
            av[e]     = (short)f2bf(lo4[e]);
            av[e + 4] = (short)f2bf(hi4[e]);
        }
        a[ks] = av;
    }
    p1 += __shfl_xor(p1, 16); p1 += __shfl_xor(p1, 32);
    p2 += __shfl_xor(p2, 16); p2 += __shfl_xor(p2, 32);
    if (w < 2 && g == 0) {
        sj[b * NN + row] = p1 + b_fc[0];
        sk[b * NN + row] = p2;
    }

    f32x4 acc[4];
    #pragma unroll
    for (int i = 0; i < 4; ++i) acc[i] = (f32x4){0.f, 0.f, 0.f, 0.f};
    #pragma unroll
    for (int i = 0; i < 4; ++i) {
        const u16* wp = Wt + (size_t)((nb + i) * 16 + sl) * CC;
        #pragma unroll
        for (int ks = 0; ks < 4; ++ks) {
            bf16x8 bv = *(const bf16x8*)(wp + ks * 32 + g * 8);
            acc[i] = __builtin_amdgcn_mfma_f32_16x16x32_bf16(a[ks], bv, acc[i], 0, 0, 0);
        }
    }
    #pragma unroll
    for (int i = 0; i < 4; ++i) {
        const int o = (nb + i) * 16 + sl;
        u16x4 h;
        #pragma unroll
        for (int e = 0; e < 4; ++e) h[e] = f2bf(acc[i][e]);
        *(u16x4*)(Yt + (size_t)(b * OO + o) * NN + k0 + mt * 16 + g * 4) = h;
    }
}

// ---------------------------------------------------------------------------
// Kernel 2: main fused aggregation — register-B variant of the proven R3
// skeleton. NO manual vmcnt anywhere (the R8-R10 failure family); the only
// LDS producer is pbuf, fenced by the proven lgkmcnt(0)+2-barrier pattern.
//   - B-fragments: direct register loads from L2-resident Yt with the
//     R6-proven fragment math (bv = Yt[(b*OO+o)*NN + kt*128 + kk*32 + kg*8]),
//     static E/O register sets, loaded at top of body t for tile t+1
//     (full-iteration slack; compiler-managed waits — no race possible).
//   - adj path, pbuf swizzle/write/read, rowsum, epilogue: VERBATIM R3.
// LDS = 8.4KB (pbuf + Sld). 512 blocks (b = bid&7 XCD-pinned), 4 waves.
// ---------------------------------------------------------------------------
__global__ __launch_bounds__(256, 2) void graphconv_main(
    const int* __restrict__ adj, const float* __restrict__ sj,
    const float* __restrict__ sk, const u16* __restrict__ Yt,
    const float* __restrict__ b_lin, float* __restrict__ out)
{
    __shared__ __align__(16) u16 pbuf[4096];      // 32 j x 16 chunks x 8
    __shared__ float Sld[32];

    const int t  = threadIdx.x;
    const int l  = t & 63, w = t >> 6;
    const int sw = l & 15, kg = l >> 4;
    const int lo = l & 31, hi = l >> 5;
    const int b  = blockIdx.x & 7;
    const int j0 = (blockIdx.x >> 3) << 5;

    // P-phase mapping (R3-proven): instr q covers rows w*8+2q+hi, 16B/lane
    const int* arow[4];
    float sjr[4];
    #pragma unroll
    for (int q = 0; q < 4; ++q) {
        const int R = j0 + w * 8 + 2 * q + hi;
        arow[q] = adj + ((size_t)b * NN + R) * NN + lo * 4;
        sjr[q]  = sj[b * NN + R];
    }
    const float* skp = sk + b * NN + lo * 4;

    // B-fragment bases (R6-proven math): o = w*32 + os*16 + sw, k-slot kg*8
    const u16* ybase[2];
    #pragma unroll
    for (int os = 0; os < 2; ++os)
        ybase[os] = Yt + (size_t)(b * OO + w * 32 + os * 16 + sw) * NN + kg * 8;

    f32x4 acc[2][2];
    #pragma unroll
    for (int js = 0; js < 2; ++js)
        #pragma unroll
        for (int os = 0; os < 2; ++os) acc[js][os] = (f32x4){0.f, 0.f, 0.f, 0.f};
    float psum[4] = {0.f, 0.f, 0.f, 0.f};

    // B register double-buffer (static E/O; indices constant after unroll)
    bf16x8 BE[8], BO[8];

#define BLOAD(T, BN)                                                          \
    {                                                                         \
        const int tt = ((T) > 15) ? 15 : (T);                                 \
        _Pragma("unroll")                                                     \
        for (int os = 0; os < 2; ++os)                                        \
            _Pragma("unroll")                                                 \
            for (int kk = 0; kk < 4; ++kk)                                    \
                BN[os * 4 + kk] =                                             \
                    *(const bf16x8*)(ybase[os] + tt * 128 + kk * 32);         \
    }

    // prologue: B(0) + adj/sk(0) + adj/sk(1)   (register loads only)
    BLOAD(0, BE)
    i32x4 a_cur[4], a_n1[4];
    f32x4 s_cur, s_n1;
    #pragma unroll
    for (int q = 0; q < 4; ++q) a_cur[q] = *(const i32x4*)(arow[q]);
    s_cur = *(const f32x4*)(skp);
    #pragma unroll
    for (int q = 0; q < 4; ++q) a_n1[q] = *(const i32x4*)(arow[q] + 128);
    s_n1 = *(const f32x4*)(skp + 128);

#define TILE_BODY(T, BC, BN)                                                  \
    {                                                                         \
        const int kt2 = ((T) < 14) ? (T) + 2 : 15;                            \
        /* B(t+1) into the alternate set: full-iteration latency slack */     \
        BLOAD((T) + 1, BN)                                                    \
        /* 2-deep adj/sk prefetch (R3-proven rotation) */                     \
        i32x4 a_n2[4]; f32x4 s_n2;                                            \
        _Pragma("unroll")                                                     \
        for (int q = 0; q < 4; ++q)                                           \
            a_n2[q] = *(const i32x4*)(arow[q] + kt2 * 128);                   \
        s_n2 = *(const f32x4*)(skp + kt2 * 128);                              \
        /* P = masked sigmoid -> pbuf (VERBATIM R3) */                        \
        u16x4 hq[4];                                                          \
        _Pragma("unroll")                                                     \
        for (int q = 0; q < 4; ++q) {                                         \
            _Pragma("unroll")                                                 \
            for (int e = 0; e < 4; ++e) {                                     \
                float z  = sjr[q] + s_cur[e];                                 \
                float sg = __builtin_amdgcn_rcpf(1.0f + __expf(-z));          \
                float pv = a_cur[q][e] ? sg : 0.0f;                           \
                psum[q] += pv;                                                \
                hq[q][e] = f2bf(pv);                                          \
            }                                                                 \
        }                                                                     \
        {                                                                     \
            const int kc = lo >> 1, hh = lo & 1;                              \
            _Pragma("unroll")                                                 \
            for (int q = 0; q < 4; ++q) {                                     \
                const int R = w * 8 + 2 * q + hi;                             \
                const int u = R * 16 + (kc ^ (R & 15));                       \
                *(u16x4*)&pbuf[u * 8 + hh * 4] = hq[q];                       \
            }                                                                 \
        }                                                                     \
        /* pbuf visible to all waves (proven 2-barrier pattern, no vmcnt) */  \
        asm volatile("s_waitcnt lgkmcnt(0)" ::: "memory");                    \
        __builtin_amdgcn_s_barrier();                                         \
        asm volatile("" ::: "memory");                                        \
        /* MFMA(T): af from pbuf (VERBATIM R3), B from registers */           \
        _Pragma("unroll")                                                     \
        for (int kk = 0; kk < 4; ++kk) {                                      \
            const int kc = kk * 4 + kg;                                       \
            bf16x8 af[2];                                                     \
            _Pragma("unroll")                                                 \
            for (int js = 0; js < 2; ++js)                                    \
                af[js] = *(const bf16x8*)&pbuf[((js * 16 + sw) * 16 + (kc ^ sw)) * 8]; \
            _Pragma("unroll")                                                 \
            for (int js = 0; js < 2; ++js)                                    \
                _Pragma("unroll")                                             \
                for (int os = 0; os < 2; ++os)                                \
                    acc[js][os] = __builtin_amdgcn_mfma_f32_16x16x32_bf16(    \
                        af[js], BC[os * 4 + kk], acc[js][os], 0, 0, 0);       \
        }                                                                     \
        asm volatile("" ::: "memory");                                        \
        __builtin_amdgcn_s_barrier();   /* pbuf reads done before next writes */ \
        asm volatile("" ::: "memory");                                        \
        /* rotate adj/sk (R3-proven) */                                       \
        _Pragma("unroll")                                                     \
        for (int q = 0; q < 4; ++q) a_cur[q] = a_n1[q];                       \
        s_cur = s_n1;                                                         \
        _Pragma("unroll")                                                     \
        for (int q = 0; q < 4; ++q) a_n1[q] = a_n2[q];                        \
        s_n1 = s_n2;                                                          \
    }

    for (int m = 0; m < 8; ++m) {
        TILE_BODY(2 * m,     BE, BO)
        TILE_BODY(2 * m + 1, BO, BE)
    }
#undef TILE_BODY
#undef BLOAD

    // rowsum reduce (VERBATIM R3)
    #pragma unroll
    for (int q = 0; q < 4; ++q) {
        float s = psum[q];
        s += __shfl_xor(s, 1); s += __shfl_xor(s, 2); s += __shfl_xor(s, 4);
        s += __shfl_xor(s, 8); s += __shfl_xor(s, 16);
        if (lo == 0) Sld[w * 8 + 2 * q + hi] = s;
    }
    __syncthreads();

    // epilogue (VERBATIM R3)
    #pragma unroll
    for (int js = 0; js < 2; ++js) {
        float rinv[4];
        #pragma unroll
        for (int i = 0; i < 4; ++i) rinv[i] = 1.0f / Sld[js * 16 + kg * 4 + i];
        #pragma unroll
        for (int os = 0; os < 2; ++os) {
            const int col = w * 32 + os * 16 + sw;
            const float bl = b_lin[col];
            #pragma unroll
            for (int i = 0; i < 4; ++i) {
                size_t row = (size_t)(b * NN + j0 + js * 16 + kg * 4 + i);
                out[row * OO + col] = acc[js][os][i] * rinv[i] + bl;
            }
        }
    }
}

extern "C" void kernel_launch(void* const* d_in, const int* in_sizes, int n_in,
                              void* d_out, int out_size, void* d_ws, size_t ws_size,
                              hipStream_t stream) {
    const float* x     = (const float*)d_in[0];
    const int*   adj   = (const int*)d_in[1];
    const float* W_fc  = (const float*)d_in[2];
    const float* b_fc  = (const float*)d_in[3];
    const float* W_lin = (const float*)d_in[4];
    const float* b_lin = (const float*)d_in[5];
    float* out = (float*)d_out;

    // workspace: Yt (bf16, 4MB) | sj (64KB) | sk (64KB) | Wt (32KB)  (proven)
    u16*   Yt = (u16*)d_ws;
    float* sj = (float*)((char*)d_ws + (size_t)BB * OO * NN * sizeof(u16));
    float* sk = sj + BB * NN;
    u16*   Wt = (u16*)(sk + BB * NN);

    wt_kernel<<<16, 256, 0, stream>>>(W_lin, Wt);
    precompute_kernel<<<512, 256, 0, stream>>>(x, W_fc, b_fc, Wt, sj, sk, Yt);
    graphconv_main<<<512, 256, 0, stream>>>(adj, sj, sk, Yt, b_lin, out);
}